// Round 6
// baseline (326.332 us; speedup 1.0000x reference)
//
#include <hip/hip_runtime.h>
#include <math.h>

#define SCALEF 0.044194173824159216f   // 1/sqrt(512)

typedef __attribute__((ext_vector_type(8))) short bf16x8;
typedef __attribute__((ext_vector_type(4))) float f32x4;

static __device__ __forceinline__ unsigned short f2bf(float f) {
    union { float f; unsigned int i; } v; v.f = f;
    return (unsigned short)((v.i + 0x7fffu + ((v.i >> 16) & 1u)) >> 16);
}
static __device__ __forceinline__ float bf2f(unsigned short h) {
    union { unsigned int i; float f; } v; v.i = ((unsigned int)h) << 16;
    return v.f;
}
static __device__ __forceinline__ void gload16(const void* g, void* l) {
    __builtin_amdgcn_global_load_lds(
        (const __attribute__((address_space(1))) unsigned int*)g,
        (__attribute__((address_space(3))) unsigned int*)l, 16, 0, 0);
}

// ---- tokens + latents f32 -> bf16, branch-free, 6 independent loads/thread --
__global__ __launch_bounds__(256) void cvt_tl(const float4* __restrict__ tok,
                                              const float4* __restrict__ lat,
                                              ushort4* __restrict__ tokd,
                                              ushort4* __restrict__ latd) {
    long t = blockIdx.x * 256L + threadIdx.x;       // grid 4096 -> 1,048,576 threads
    #pragma unroll
    for (int k = 0; k < 5; ++k) {
        long i = t + k * 1048576L;
        float4 f = tok[i];
        ushort4 u; u.x = f2bf(f.x); u.y = f2bf(f.y); u.z = f2bf(f.z); u.w = f2bf(f.w);
        tokd[i] = u;
    }
    {
        float4 f = lat[t];
        ushort4 u; u.x = f2bf(f.x); u.y = f2bf(f.y); u.z = f2bf(f.z); u.w = f2bf(f.w);
        latd[t] = u;
    }
}

// ---- rest of prep: 4 weights + conv pack ----
__global__ __launch_bounds__(256) void prep_rest(
    const float4* __restrict__ wl, const float4* __restrict__ wt,
    const float4* __restrict__ wvl, const float4* __restrict__ wvt,
    const float* __restrict__ cw,
    ushort4* __restrict__ wlb, ushort4* __restrict__ wtb,
    ushort4* __restrict__ wvlb, ushort4* __restrict__ wvtb,
    unsigned int* __restrict__ wpb)
{
    const long NW = 65536, NCV = 327680;
    for (long i = blockIdx.x * 256L + threadIdx.x; i < 4 * NW + NCV;
         i += gridDim.x * 256L) {
        long r = i;
        const float4* s = nullptr; ushort4* d = nullptr;
        if (r < NW) { s = wl; d = wlb; }
        else if ((r -= NW) < NW) { s = wt; d = wtb; }
        else if ((r -= NW) < NW) { s = wvl; d = wvlb; }
        else if ((r -= NW) < NW) { s = wvt; d = wvtb; }
        else {
            r -= NW;  // conv unit: wp[e][k*128+c2] = {cw[e][2c2][k], cw[e][2c2+1][k]}
            long e = r / 640, rr = r % 640, k = rr >> 7, c2 = rr & 127;
            unsigned int lo = f2bf(cw[e * 1280 + (2 * c2) * 5 + k]);
            unsigned int hi = f2bf(cw[e * 1280 + (2 * c2 + 1) * 5 + k]);
            wpb[r] = lo | (hi << 16);
            continue;
        }
        float4 f = s[r];
        ushort4 u; u.x = f2bf(f.x); u.y = f2bf(f.y); u.z = f2bf(f.z); u.w = f2bf(f.w);
        d[r] = u;
    }
}

// ---------------- bf16 transpose: ST[b][s][l] = S[b][l][s] ----------------
__global__ __launch_bounds__(256) void transpose_bf(const unsigned short* __restrict__ S,
                                                    unsigned short* __restrict__ ST) {
    __shared__ unsigned short tl[64][66];
    const int b = blockIdx.z, r0 = blockIdx.y << 6, c0 = blockIdx.x << 6;
    const unsigned short* Sb = S + ((long)b << 21);
    unsigned short* Tb = ST + ((long)b << 21);
    const int t32 = threadIdx.x & 31, trow = threadIdx.x >> 5;
    #pragma unroll
    for (int i = 0; i < 8; ++i) {
        int r = trow + i * 8;
        unsigned int v = *(const unsigned int*)&Sb[(long)(r0 + r) * 2048 + c0 + t32 * 2];
        *(unsigned int*)&tl[r][t32 * 2] = v;
    }
    __syncthreads();
    #pragma unroll
    for (int i = 0; i < 8; ++i) {
        int c = trow + i * 8;
        unsigned int lo = tl[t32 * 2][c], hi = tl[t32 * 2 + 1][c];
        *(unsigned int*)&Tb[(long)(c0 + c) * 1024 + r0 + t32 * 2] = lo | (hi << 16);
    }
}

// ------------- in-place row softmax body (bf16), 1/sum folded in -------------
template<int RL>
static __device__ __forceinline__ void sm_body(unsigned short* __restrict__ rowp,
                                               float* __restrict__ redm,
                                               float* __restrict__ reds) {
    constexpr int U = RL / 512;                 // u32 words per thread
    unsigned int* p = (unsigned int*)rowp;
    const int t = threadIdx.x, lane = t & 63, wid = t >> 6;
    unsigned int u[U];
    float v[2 * U];
    #pragma unroll
    for (int i = 0; i < U; ++i) u[i] = p[t + (i << 8)];
    #pragma unroll
    for (int i = 0; i < U; ++i) {
        v[2 * i]     = bf2f((unsigned short)(u[i] & 0xffffu));
        v[2 * i + 1] = bf2f((unsigned short)(u[i] >> 16));
    }
    float m = -INFINITY;
    #pragma unroll
    for (int i = 0; i < 2 * U; ++i) m = fmaxf(m, v[i]);
    #pragma unroll
    for (int k = 1; k < 64; k <<= 1) m = fmaxf(m, __shfl_xor(m, k));
    if (lane == 0) redm[wid] = m;
    __syncthreads();
    m = fmaxf(fmaxf(redm[0], redm[1]), fmaxf(redm[2], redm[3]));
    float s = 0.f, e[2 * U];
    #pragma unroll
    for (int i = 0; i < 2 * U; ++i) { e[i] = __expf(v[i] - m); s += e[i]; }
    #pragma unroll
    for (int k = 1; k < 64; k <<= 1) s += __shfl_xor(s, k);
    if (lane == 0) reds[wid] = s;
    __syncthreads();
    s = reds[0] + reds[1] + reds[2] + reds[3];
    float inv = 1.f / s;
    #pragma unroll
    for (int i = 0; i < U; ++i) {
        unsigned int lo = f2bf(e[2 * i] * inv);
        unsigned int hi = f2bf(e[2 * i + 1] * inv);
        p[t + (i << 8)] = lo | (hi << 16);
    }
}

__global__ __launch_bounds__(256) void softmax_both(unsigned short* __restrict__ S,
                                                    unsigned short* __restrict__ ST) {
    __shared__ float redm[4], reds[4];
    long b = blockIdx.x;
    if (b < 8192) sm_body<2048>(S + b * 2048L, redm, reds);
    else          sm_body<1024>(ST + (b - 8192) * 1024L, redm, reds);
}

// ---------------- unified MFMA NT GEMM with runtime config ----------------
// C[m,n] = sum_k A[m,k] * B[n,k]; 128x128 tile, BK=32, 4 waves, triple-buffered
// depth-2 prefetch with counted vmcnt (as r5, proven).  Epilogue staged through
// LDS (f32 [64][132], 2 rounds) -> fully coalesced 16B global loads/stores.
// epi: 0 = bf16 out * scale; 1 = +bias(f32) -> bf16; 2 = f32 base + acc -> C0,C1;
//      3 = bf16 base + acc -> C0,C1.   amode: 0 = row-major A; 1 = conv addressing.
struct Cfg {
    const unsigned short *A, *B;
    long bsA, bsB;
    int lda, ldb, K;
    unsigned short* Cb; long bsCb;
    float *C0, *C1; long bsC0, bsC1;
    const void* basep; long bsBase;
    int ldc; float scale;
    int nx, ny;        // grid decode: bx = l%nx, by = (l/nx)%ny, z = l/(nx*ny)
    int epi, amode, nblocks;
};

__global__ __launch_bounds__(256) void mm_multi(Cfg c0, Cfg c1, Cfg c2, Cfg c3) {
    __shared__ float4 smq[3072];                // 49152 B: 3 bufs x 16KB, reused by epilogue
    char* smc = (char*)smq;
    const int bid = blockIdx.x;
    const int t = threadIdx.x, lane = t & 63, wid = t >> 6;

    Cfg c; int local;
    {
        int e0 = c0.nblocks, e1 = e0 + c1.nblocks, e2 = e1 + c2.nblocks;
        if      (bid < e0) { c = c0; local = bid; }
        else if (bid < e1) { c = c1; local = bid - e0; }
        else if (bid < e2) { c = c2; local = bid - e1; }
        else               { c = c3; local = bid - e2; }
    }
    const int bx = local % c.nx;
    const int t2 = local / c.nx;
    const int by = t2 % c.ny;
    const int z  = t2 / c.ny;
    const int m0 = by << 7, n0 = bx << 7;

    const unsigned short* Ab = c.A + (long)z * c.bsA;
    const unsigned short* Bb = c.B + (long)z * c.bsB;

    const int rA0 = wid * 16 + (lane >> 2);
    const int rA1 = rA0 + 64;
    const int cs0 = (lane & 3) ^ ((rA0 >> 1) & 3);
    const int cs1 = (lane & 3) ^ ((rA1 >> 1) & 3);

    long aoff0, aoff1;
    if (c.amode == 0) {
        aoff0 = (long)(m0 + rA0) * c.lda + cs0 * 8;
        aoff1 = (long)(m0 + rA1) * c.lda + cs1 * 8;
    } else {
        int ma = m0 + rA0, mb = m0 + rA1;
        aoff0 = (long)(ma >> 11) * 2621440 + (long)(ma & 2047) * 1280 + cs0 * 8;
        aoff1 = (long)(mb >> 11) * 2621440 + (long)(mb & 2047) * 1280 + cs1 * 8;
    }
    const long boff0 = (long)(n0 + rA0) * c.ldb + cs0 * 8;
    const long boff1 = (long)(n0 + rA1) * c.ldb + cs1 * 8;

    const int dA0 = (wid << 10), dA1 = ((wid + 4) << 10);
    const int dB0 = 8192 + (wid << 10), dB1 = 8192 + ((wid + 4) << 10);

    const int wr = wid >> 1, wc = wid & 1;
    const int l15 = lane & 15, cslot = lane >> 4;
    int offA[4], offB[4];
    #pragma unroll
    for (int i = 0; i < 4; ++i) {
        int r = wr * 64 + i * 16 + l15;
        offA[i] = r * 64 + ((cslot ^ ((r >> 1) & 3)) << 4);
        int rb = wc * 64 + i * 16 + l15;
        offB[i] = 8192 + rb * 64 + ((cslot ^ ((rb >> 1) & 3)) << 4);
    }

    f32x4 acc[4][4];
    #pragma unroll
    for (int i = 0; i < 4; ++i)
        #pragma unroll
        for (int j = 0; j < 4; ++j)
            acc[i][j] = (f32x4)(0.f);

#define STAGE(p, ktv) do {                                   \
        int kb_ = (ktv);                                     \
        int bo_ = (p) * 16384;                               \
        gload16(Ab + aoff0 + kb_, smc + bo_ + dA0);          \
        gload16(Ab + aoff1 + kb_, smc + bo_ + dA1);          \
        gload16(Bb + boff0 + kb_, smc + bo_ + dB0);          \
        gload16(Bb + boff1 + kb_, smc + bo_ + dB1);          \
    } while (0)

    const int nt = c.K >> 5;                    // always >= 2 here
    STAGE(0, 0);
    STAGE(1, 32);
    int cur = 0;
    for (int it = 0; it < nt; ++it) {
        if (it + 2 < nt) {
            int nx2 = (cur >= 1) ? cur - 1 : 2;   // (cur+2)%3
            STAGE(nx2, (it + 2) << 5);
            asm volatile("s_waitcnt vmcnt(8)" ::: "memory");
        } else if (it + 1 < nt) {
            asm volatile("s_waitcnt vmcnt(4)" ::: "memory");
        } else {
            asm volatile("s_waitcnt vmcnt(0)" ::: "memory");
        }
        __builtin_amdgcn_s_barrier();
        const char* base = smc + cur * 16384;
        bf16x8 af[4], bfr[4];
        #pragma unroll
        for (int i = 0; i < 4; ++i) af[i]  = *(const bf16x8*)(base + offA[i]);
        #pragma unroll
        for (int i = 0; i < 4; ++i) bfr[i] = *(const bf16x8*)(base + offB[i]);
        #pragma unroll
        for (int i = 0; i < 4; ++i)
            #pragma unroll
            for (int j = 0; j < 4; ++j)
                acc[i][j] = __builtin_amdgcn_mfma_f32_16x16x32_bf16(af[i], bfr[j], acc[i][j], 0, 0, 0);
        asm volatile("s_waitcnt lgkmcnt(0)" ::: "memory");
        __builtin_amdgcn_s_barrier();
        cur = (cur + 1 == 3) ? 0 : cur + 1;
    }
#undef STAGE

    // ---- epilogue: stage acc through LDS, 2 rounds of 64 rows, 16B global I/O
    float* ep = (float*)smc;                    // [64][132] f32 = 33792 B
    const int er = t >> 2, ecg = t & 3;         // row 0..63, col-group 0..3
    #pragma unroll
    for (int h = 0; h < 2; ++h) {
        __syncthreads();
        if (wr == h) {
            #pragma unroll
            for (int i = 0; i < 4; ++i)
                #pragma unroll
                for (int j = 0; j < 4; ++j)
                    #pragma unroll
                    for (int q = 0; q < 4; ++q)
                        ep[(i * 16 + cslot * 4 + q) * 132 + wc * 64 + j * 16 + l15] = acc[i][j][q];
        }
        __syncthreads();
        const int m = m0 + h * 64 + er;
        const int nc = n0 + ecg * 32;
        float v[32];
        #pragma unroll
        for (int j = 0; j < 8; ++j)
            *(float4*)&v[j * 4] = *(const float4*)&ep[er * 132 + ecg * 32 + j * 4];

        if (c.epi == 0) {
            unsigned int u[16];
            #pragma unroll
            for (int k = 0; k < 16; ++k) {
                unsigned int lo = f2bf(v[2 * k] * c.scale);
                unsigned int hi = f2bf(v[2 * k + 1] * c.scale);
                u[k] = lo | (hi << 16);
            }
            unsigned int* dst = (unsigned int*)(c.Cb + (long)z * c.bsCb + (long)m * c.ldc + nc);
            #pragma unroll
            for (int j = 0; j < 4; ++j)
                *(uint4*)(dst + j * 4) = *(uint4*)&u[j * 4];
        } else if (c.epi == 1) {
            const float* bp = (const float*)c.basep + nc;
            float bb[32];
            #pragma unroll
            for (int j = 0; j < 8; ++j) *(float4*)&bb[j * 4] = *(const float4*)(bp + j * 4);
            unsigned int u[16];
            #pragma unroll
            for (int k = 0; k < 16; ++k) {
                unsigned int lo = f2bf(v[2 * k] + bb[2 * k]);
                unsigned int hi = f2bf(v[2 * k + 1] + bb[2 * k + 1]);
                u[k] = lo | (hi << 16);
            }
            unsigned int* dst = (unsigned int*)(c.Cb + (long)m * c.ldc + nc);
            #pragma unroll
            for (int j = 0; j < 4; ++j)
                *(uint4*)(dst + j * 4) = *(uint4*)&u[j * 4];
        } else if (c.epi == 2) {
            const float* bp = (const float*)c.basep + (long)z * c.bsBase + (long)m * c.ldc + nc;
            float* o0 = c.C0 + (long)z * c.bsC0 + (long)m * c.ldc + nc;
            float* o1 = c.C1 + (long)z * c.bsC1 + (long)m * c.ldc + nc;
            #pragma unroll
            for (int j = 0; j < 8; ++j) {
                float4 b4 = *(const float4*)(bp + j * 4);
                float4 o; o.x = b4.x + v[j*4]; o.y = b4.y + v[j*4+1];
                o.z = b4.z + v[j*4+2]; o.w = b4.w + v[j*4+3];
                *(float4*)(o0 + j * 4) = o;
                *(float4*)(o1 + j * 4) = o;
            }
        } else {
            const unsigned short* bp = (const unsigned short*)c.basep + (long)z * c.bsBase + (long)m * c.ldc + nc;
            float* o0 = c.C0 + (long)z * c.bsC0 + (long)m * c.ldc + nc;
            float* o1 = c.C1 + (long)z * c.bsC1 + (long)m * c.ldc + nc;
            #pragma unroll
            for (int j = 0; j < 8; ++j) {
                uint2 w = *(const uint2*)(bp + j * 4);
                float4 o;
                o.x = bf2f((unsigned short)(w.x & 0xffffu)) + v[j*4];
                o.y = bf2f((unsigned short)(w.x >> 16))     + v[j*4+1];
                o.z = bf2f((unsigned short)(w.y & 0xffffu)) + v[j*4+2];
                o.w = bf2f((unsigned short)(w.y >> 16))     + v[j*4+3];
                *(float4*)(o0 + j * 4) = o;
                *(float4*)(o1 + j * 4) = o;
            }
        }
    }
}

static Cfg mk(const unsigned short* A, const unsigned short* B, long bsA, long bsB,
              int lda, int ldb, int K, unsigned short* Cb, long bsCb,
              float* C0, long bsC0, float* C1, long bsC1,
              const void* basep, long bsBase, int ldc, float scale,
              int nx, int ny, int nz, int epi, int amode) {
    Cfg c; c.A = A; c.B = B; c.bsA = bsA; c.bsB = bsB; c.lda = lda; c.ldb = ldb;
    c.K = K; c.Cb = Cb; c.bsCb = bsCb; c.C0 = C0; c.bsC0 = bsC0; c.C1 = C1;
    c.bsC1 = bsC1; c.basep = basep; c.bsBase = bsBase; c.ldc = ldc; c.scale = scale;
    c.nx = nx; c.ny = ny; c.epi = epi; c.amode = amode; c.nblocks = nx * ny * nz;
    return c;
}

extern "C" void kernel_launch(void* const* d_in, const int* in_sizes, int n_in,
                              void* d_out, int out_size, void* d_ws, size_t ws_size,
                              hipStream_t stream)
{
    const float* latents = (const float*)d_in[0];
    const float* tokens  = (const float*)d_in[1];
    const float* W_lat   = (const float*)d_in[2];
    const float* W_tok   = (const float*)d_in[3];
    const float* W_vlat  = (const float*)d_in[4];
    const float* W_vtok  = (const float*)d_in[5];
    const float* conv_w  = (const float*)d_in[6];
    const float* conv_b  = (const float*)d_in[7];
    float* out = (float*)d_out;
    char* ws = (char*)d_ws;

    // workspace layout (bytes)
    unsigned short* S    = (unsigned short*)(ws);              // 8x1024x2048 bf16 = 33,554,432
    unsigned short* ST   = (unsigned short*)(ws + 33554432);   // 8x2048x1024 bf16
    unsigned short* tokb = (unsigned short*)(ws + 67108864);   // 8x2048x512  bf16 = 16,777,216
    unsigned short* latb = (unsigned short*)(ws + 83886080);   // 8x1024x512  bf16 =  8,388,608
    unsigned short* rlat = (unsigned short*)(ws + 92274688);   //  8,388,608
    unsigned short* rtok = (unsigned short*)(ws + 100663296);  // 16,777,216
    unsigned short* vlT  = (unsigned short*)(ws + 117440512);  // 8x512x1024 =  8,388,608
    unsigned short* vtT  = (unsigned short*)(ws + 125829120);  // 8x512x2048 = 16,777,216
    unsigned short* wpb  = (unsigned short*)(ws + 142606336);  // 512x1280   =  1,310,720
    unsigned short* wlb  = (unsigned short*)(ws + 143917056);  // 512x512 x4 =  2,097,152
    unsigned short* wtb  = (unsigned short*)(ws + 144441344);
    unsigned short* wvlb = (unsigned short*)(ws + 144965632);
    unsigned short* wvtb = (unsigned short*)(ws + 145489920);  // end 146,014,208
    // tokens-as-bf16 scratch lives in the concat region of d_out (overwritten later)
    unsigned short* tknb = (unsigned short*)(out + 12582912);  // 41,943,040 B <= 50,331,648 B

    // 1) conversions + conv weight pack
    cvt_tl<<<4096, 256, 0, stream>>>((const float4*)tokens, (const float4*)latents,
                                     (ushort4*)tknb, (ushort4*)latb);
    prep_rest<<<512, 256, 0, stream>>>(
        (const float4*)W_lat, (const float4*)W_tok,
        (const float4*)W_vlat, (const float4*)W_vtok, conv_w,
        (ushort4*)wlb, (ushort4*)wtb, (ushort4*)wvlb, (ushort4*)wvtb,
        (unsigned int*)wpb);

    // 2) conv-as-GEMM: tok_bf[16384][512], +bias
    Cfg cc = mk(tknb, wpb, 0, 0, 1280, 1280, 1280, tokb, 0,
                nullptr, 0, nullptr, 0, conv_b, 0, 512, 1.f, 4, 128, 1, 1, 1);
    mm_multi<<<512, 256, 0, stream>>>(cc, cc, cc, cc);

    // 3) all four projections in ONE launch (1536 blocks)
    Cfg p0 = mk(latb, wlb, 0, 0, 512, 512, 512, rlat, 0,
                nullptr, 0, nullptr, 0, nullptr, 0, 512, 1.f, 4, 64, 1, 0, 0);
    Cfg p1 = mk(tokb, wtb, 0, 0, 512, 512, 512, rtok, 0,
                nullptr, 0, nullptr, 0, nullptr, 0, 512, 1.f, 4, 128, 1, 0, 0);
    Cfg p2 = mk(wvlb, latb, 0, 524288, 512, 512, 512, vlT, 524288,
                nullptr, 0, nullptr, 0, nullptr, 0, 1024, 1.f, 8, 4, 8, 0, 0);
    Cfg p3 = mk(wvtb, tokb, 0, 1048576, 512, 512, 512, vtT, 1048576,
                nullptr, 0, nullptr, 0, nullptr, 0, 2048, 1.f, 16, 4, 8, 0, 0);
    mm_multi<<<1536, 256, 0, stream>>>(p0, p1, p2, p3);

    // 4) score matrix S = scale * Rlat Rtok^T; ST by transpose (same bf16 values)
    Cfg sc = mk(rlat, rtok, 524288, 1048576, 512, 512, 512, S, 2097152,
                nullptr, 0, nullptr, 0, nullptr, 0, 2048, SCALEF, 16, 8, 8, 0, 0);
    mm_multi<<<1024, 256, 0, stream>>>(sc, sc, sc, sc);
    transpose_bf<<<dim3(32, 16, 8), 256, 0, stream>>>(S, ST);

    // 5) softmax in place, both matrices, one launch
    softmax_both<<<24576, 256, 0, stream>>>(S, ST);

    // 6) both delta GEMMs in ONE launch (768 blocks), fused residual + dual write
    Cfg d0 = mk(S, vtT, 2097152, 1048576, 2048, 2048, 2048, nullptr, 0,
                out, 524288, out + 12582912, 1572864, latents, 524288, 512, 1.f,
                4, 8, 8, 2, 0);
    Cfg d1 = mk(ST, vlT, 2097152, 524288, 1024, 1024, 1024, nullptr, 0,
                out + 4194304, 1048576, out + 12582912 + 524288, 1572864, tokb, 1048576, 512, 1.f,
                4, 16, 8, 3, 0);
    mm_multi<<<768, 256, 0, stream>>>(d0, d1, d1, d1);
}

// Round 7
// 285.814 us; speedup vs baseline: 1.1418x; 1.1418x over previous
//
#include <hip/hip_runtime.h>
#include <math.h>

#define SCALEF 0.044194173824159216f   // 1/sqrt(512)

typedef __attribute__((ext_vector_type(8))) short bf16x8;
typedef __attribute__((ext_vector_type(4))) float f32x4;

static __device__ __forceinline__ unsigned short f2bf(float f) {
    union { float f; unsigned int i; } v; v.f = f;
    return (unsigned short)((v.i + 0x7fffu + ((v.i >> 16) & 1u)) >> 16);
}
static __device__ __forceinline__ float bf2f(unsigned short h) {
    union { unsigned int i; float f; } v; v.i = ((unsigned int)h) << 16;
    return v.f;
}
static __device__ __forceinline__ void gload16(const void* g, void* l) {
    __builtin_amdgcn_global_load_lds(
        (const __attribute__((address_space(1))) unsigned int*)g,
        (__attribute__((address_space(3))) unsigned int*)l, 16, 0, 0);
}

// ---- tokens + latents f32 -> bf16, branch-free, 6 independent loads/thread --
__global__ __launch_bounds__(256) void cvt_tl(const float4* __restrict__ tok,
                                              const float4* __restrict__ lat,
                                              ushort4* __restrict__ tokd,
                                              ushort4* __restrict__ latd) {
    long t = blockIdx.x * 256L + threadIdx.x;       // grid 4096 -> 1,048,576 threads
    #pragma unroll
    for (int k = 0; k < 5; ++k) {
        long i = t + k * 1048576L;
        float4 f = tok[i];
        ushort4 u; u.x = f2bf(f.x); u.y = f2bf(f.y); u.z = f2bf(f.z); u.w = f2bf(f.w);
        tokd[i] = u;
    }
    {
        float4 f = lat[t];
        ushort4 u; u.x = f2bf(f.x); u.y = f2bf(f.y); u.z = f2bf(f.z); u.w = f2bf(f.w);
        latd[t] = u;
    }
}

// ---- rest of prep: 4 weights + conv pack ----
__global__ __launch_bounds__(256) void prep_rest(
    const float4* __restrict__ wl, const float4* __restrict__ wt,
    const float4* __restrict__ wvl, const float4* __restrict__ wvt,
    const float* __restrict__ cw,
    ushort4* __restrict__ wlb, ushort4* __restrict__ wtb,
    ushort4* __restrict__ wvlb, ushort4* __restrict__ wvtb,
    unsigned int* __restrict__ wpb)
{
    const long NW = 65536, NCV = 327680;
    for (long i = blockIdx.x * 256L + threadIdx.x; i < 4 * NW + NCV;
         i += gridDim.x * 256L) {
        long r = i;
        const float4* s = nullptr; ushort4* d = nullptr;
        if (r < NW) { s = wl; d = wlb; }
        else if ((r -= NW) < NW) { s = wt; d = wtb; }
        else if ((r -= NW) < NW) { s = wvl; d = wvlb; }
        else if ((r -= NW) < NW) { s = wvt; d = wvtb; }
        else {
            r -= NW;  // conv unit: wp[e][k*128+c2] = {cw[e][2c2][k], cw[e][2c2+1][k]}
            long e = r / 640, rr = r % 640, k = rr >> 7, c2 = rr & 127;
            unsigned int lo = f2bf(cw[e * 1280 + (2 * c2) * 5 + k]);
            unsigned int hi = f2bf(cw[e * 1280 + (2 * c2 + 1) * 5 + k]);
            wpb[r] = lo | (hi << 16);
            continue;
        }
        float4 f = s[r];
        ushort4 u; u.x = f2bf(f.x); u.y = f2bf(f.y); u.z = f2bf(f.z); u.w = f2bf(f.w);
        d[r] = u;
    }
}

// ---------------- bf16 transpose: ST[b][s][l] = S[b][l][s] ----------------
__global__ __launch_bounds__(256) void transpose_bf(const unsigned short* __restrict__ S,
                                                    unsigned short* __restrict__ ST) {
    __shared__ unsigned short tl[64][66];
    const int b = blockIdx.z, r0 = blockIdx.y << 6, c0 = blockIdx.x << 6;
    const unsigned short* Sb = S + ((long)b << 21);
    unsigned short* Tb = ST + ((long)b << 21);
    const int t32 = threadIdx.x & 31, trow = threadIdx.x >> 5;
    #pragma unroll
    for (int i = 0; i < 8; ++i) {
        int r = trow + i * 8;
        unsigned int v = *(const unsigned int*)&Sb[(long)(r0 + r) * 2048 + c0 + t32 * 2];
        *(unsigned int*)&tl[r][t32 * 2] = v;
    }
    __syncthreads();
    #pragma unroll
    for (int i = 0; i < 8; ++i) {
        int c = trow + i * 8;
        unsigned int lo = tl[t32 * 2][c], hi = tl[t32 * 2 + 1][c];
        *(unsigned int*)&Tb[(long)(c0 + c) * 1024 + r0 + t32 * 2] = lo | (hi << 16);
    }
}

// ------------- in-place row softmax body (bf16), 1/sum folded in -------------
template<int RL>
static __device__ __forceinline__ void sm_body(unsigned short* __restrict__ rowp,
                                               float* __restrict__ redm,
                                               float* __restrict__ reds) {
    constexpr int U = RL / 512;                 // u32 words per thread
    unsigned int* p = (unsigned int*)rowp;
    const int t = threadIdx.x, lane = t & 63, wid = t >> 6;
    unsigned int u[U];
    float v[2 * U];
    #pragma unroll
    for (int i = 0; i < U; ++i) u[i] = p[t + (i << 8)];
    #pragma unroll
    for (int i = 0; i < U; ++i) {
        v[2 * i]     = bf2f((unsigned short)(u[i] & 0xffffu));
        v[2 * i + 1] = bf2f((unsigned short)(u[i] >> 16));
    }
    float m = -INFINITY;
    #pragma unroll
    for (int i = 0; i < 2 * U; ++i) m = fmaxf(m, v[i]);
    #pragma unroll
    for (int k = 1; k < 64; k <<= 1) m = fmaxf(m, __shfl_xor(m, k));
    if (lane == 0) redm[wid] = m;
    __syncthreads();
    m = fmaxf(fmaxf(redm[0], redm[1]), fmaxf(redm[2], redm[3]));
    float s = 0.f, e[2 * U];
    #pragma unroll
    for (int i = 0; i < 2 * U; ++i) { e[i] = __expf(v[i] - m); s += e[i]; }
    #pragma unroll
    for (int k = 1; k < 64; k <<= 1) s += __shfl_xor(s, k);
    if (lane == 0) reds[wid] = s;
    __syncthreads();
    s = reds[0] + reds[1] + reds[2] + reds[3];
    float inv = 1.f / s;
    #pragma unroll
    for (int i = 0; i < U; ++i) {
        unsigned int lo = f2bf(e[2 * i] * inv);
        unsigned int hi = f2bf(e[2 * i + 1] * inv);
        p[t + (i << 8)] = lo | (hi << 16);
    }
}

__global__ __launch_bounds__(256) void softmax_both(unsigned short* __restrict__ S,
                                                    unsigned short* __restrict__ ST) {
    __shared__ float redm[4], reds[4];
    long b = blockIdx.x;
    if (b < 8192) sm_body<2048>(S + b * 2048L, redm, reds);
    else          sm_body<1024>(ST + (b - 8192) * 1024L, redm, reds);
}

// ---------------- MFMA NT GEMM: C[m,n] = sum_k A[m,k] * B[n,k] ----------------
// 128x128 tile, BK=32, 4 waves (2x2 of 64x64), 16x16x32 bf16 MFMA.
// Triple-buffered LDS, depth-2 prefetch, counted vmcnt (r5-proven loop).
// Epilogue staged through LDS (f32 [64][132], 2 rounds) -> coalesced 16B I/O.
// All config compile-time (template) or scalar args -> zero scratch (r6 lesson:
// runtime-selected Cfg aggregate went to local memory, 2.7x WRITE_SIZE).
// AMODE: 0 = row m at A + m*lda.  1 = conv addressing into raw tokens (bf16).
// EPI:   0 = bf16 out (Cb) * scale
//        1 = +bias(f32, basep) then bf16 out (Cb)
//        2 = f32 base (basep) + acc -> C0 and C1
//        3 = bf16 base (basep) + acc -> C0 and C1
template<int AMODE, int EPI>
__global__ __launch_bounds__(256) void mm_nt(
    const unsigned short* __restrict__ A, const unsigned short* __restrict__ B,
    long bsA, long bsB, int lda, int ldb, int K,
    unsigned short* __restrict__ Cb, long bsCb,
    float* __restrict__ C0, long bsC0, float* __restrict__ C1, long bsC1,
    const void* __restrict__ basep, long bsBase, int ldc, float scale)
{
    __shared__ unsigned short sm[24576];        // 48KB: 3 bufs x (A 8KB + B 8KB)
    char* smc = (char*)sm;
    const int t = threadIdx.x, lane = t & 63, wid = t >> 6;
    const int z = blockIdx.z;
    const int m0 = blockIdx.y << 7, n0 = blockIdx.x << 7;
    const unsigned short* Ab = A + (long)z * bsA;
    const unsigned short* Bb = B + (long)z * bsB;

    const int rA0 = wid * 16 + (lane >> 2);
    const int rA1 = rA0 + 64;
    const int cs0 = (lane & 3) ^ ((rA0 >> 1) & 3);
    const int cs1 = (lane & 3) ^ ((rA1 >> 1) & 3);

    long aoff0, aoff1;
    if (AMODE == 0) {
        aoff0 = (long)(m0 + rA0) * lda + cs0 * 8;
        aoff1 = (long)(m0 + rA1) * lda + cs1 * 8;
    } else {
        int ma = m0 + rA0, mb = m0 + rA1;
        aoff0 = (long)(ma >> 11) * 2621440 + (long)(ma & 2047) * 1280 + cs0 * 8;
        aoff1 = (long)(mb >> 11) * 2621440 + (long)(mb & 2047) * 1280 + cs1 * 8;
    }
    const long boff0 = (long)(n0 + rA0) * ldb + cs0 * 8;
    const long boff1 = (long)(n0 + rA1) * ldb + cs1 * 8;

    const int dA0 = (wid << 10), dA1 = ((wid + 4) << 10);
    const int dB0 = 8192 + (wid << 10), dB1 = 8192 + ((wid + 4) << 10);

    const int wr = wid >> 1, wc = wid & 1;
    const int l15 = lane & 15, cslot = lane >> 4;
    int offA[4], offB[4];
    #pragma unroll
    for (int i = 0; i < 4; ++i) {
        int r = wr * 64 + i * 16 + l15;
        offA[i] = r * 64 + ((cslot ^ ((r >> 1) & 3)) << 4);
        int rb = wc * 64 + i * 16 + l15;
        offB[i] = 8192 + rb * 64 + ((cslot ^ ((rb >> 1) & 3)) << 4);
    }

    f32x4 acc[4][4];
    #pragma unroll
    for (int i = 0; i < 4; ++i)
        #pragma unroll
        for (int j = 0; j < 4; ++j)
            acc[i][j] = (f32x4)(0.f);

#define STAGE(p, ktv) do {                                   \
        int kb_ = (ktv);                                     \
        int bo_ = (p) * 16384;                               \
        gload16(Ab + aoff0 + kb_, smc + bo_ + dA0);          \
        gload16(Ab + aoff1 + kb_, smc + bo_ + dA1);          \
        gload16(Bb + boff0 + kb_, smc + bo_ + dB0);          \
        gload16(Bb + boff1 + kb_, smc + bo_ + dB1);          \
    } while (0)

    const int nt = K >> 5;                      // always >= 2 here
    STAGE(0, 0);
    STAGE(1, 32);
    int cur = 0;
    for (int it = 0; it < nt; ++it) {
        if (it + 2 < nt) {
            int nx2 = (cur >= 1) ? cur - 1 : 2;   // (cur+2)%3
            STAGE(nx2, (it + 2) << 5);
            asm volatile("s_waitcnt vmcnt(8)" ::: "memory");
        } else if (it + 1 < nt) {
            asm volatile("s_waitcnt vmcnt(4)" ::: "memory");
        } else {
            asm volatile("s_waitcnt vmcnt(0)" ::: "memory");
        }
        __builtin_amdgcn_s_barrier();
        const char* base = smc + cur * 16384;
        bf16x8 af[4], bfr[4];
        #pragma unroll
        for (int i = 0; i < 4; ++i) af[i]  = *(const bf16x8*)(base + offA[i]);
        #pragma unroll
        for (int i = 0; i < 4; ++i) bfr[i] = *(const bf16x8*)(base + offB[i]);
        #pragma unroll
        for (int i = 0; i < 4; ++i)
            #pragma unroll
            for (int j = 0; j < 4; ++j)
                acc[i][j] = __builtin_amdgcn_mfma_f32_16x16x32_bf16(af[i], bfr[j], acc[i][j], 0, 0, 0);
        asm volatile("s_waitcnt lgkmcnt(0)" ::: "memory");
        __builtin_amdgcn_s_barrier();
        cur = (cur + 1 == 3) ? 0 : cur + 1;
    }
#undef STAGE

    // ---- epilogue: stage acc through LDS, 2 rounds of 64 rows, 16B global I/O
    // C/D frag layout col=lane&15, row=(lane>>4)*4+q [m89-verified]; validated r6.
    float* ep = (float*)smc;                    // [64][132] f32 = 33792 B
    const int er = t >> 2, ecg = t & 3;         // row 0..63, col-group 0..3
    #pragma unroll
    for (int h = 0; h < 2; ++h) {
        __syncthreads();
        if (wr == h) {
            #pragma unroll
            for (int i = 0; i < 4; ++i)
                #pragma unroll
                for (int j = 0; j < 4; ++j)
                    #pragma unroll
                    for (int q = 0; q < 4; ++q)
                        ep[(i * 16 + cslot * 4 + q) * 132 + wc * 64 + j * 16 + l15] = acc[i][j][q];
        }
        __syncthreads();
        const int m = m0 + h * 64 + er;
        const int nc = n0 + ecg * 32;
        float v[32];
        #pragma unroll
        for (int j = 0; j < 8; ++j)
            *(float4*)&v[j * 4] = *(const float4*)&ep[er * 132 + ecg * 32 + j * 4];

        if (EPI == 0) {
            unsigned int u[16];
            #pragma unroll
            for (int k = 0; k < 16; ++k) {
                unsigned int lo = f2bf(v[2 * k] * scale);
                unsigned int hi = f2bf(v[2 * k + 1] * scale);
                u[k] = lo | (hi << 16);
            }
            unsigned int* dst = (unsigned int*)(Cb + (long)z * bsCb + (long)m * ldc + nc);
            #pragma unroll
            for (int j = 0; j < 4; ++j)
                *(uint4*)(dst + j * 4) = *(uint4*)&u[j * 4];
        } else if (EPI == 1) {
            const float* bp = (const float*)basep + nc;
            float bb[32];
            #pragma unroll
            for (int j = 0; j < 8; ++j) *(float4*)&bb[j * 4] = *(const float4*)(bp + j * 4);
            unsigned int u[16];
            #pragma unroll
            for (int k = 0; k < 16; ++k) {
                unsigned int lo = f2bf(v[2 * k] + bb[2 * k]);
                unsigned int hi = f2bf(v[2 * k + 1] + bb[2 * k + 1]);
                u[k] = lo | (hi << 16);
            }
            unsigned int* dst = (unsigned int*)(Cb + (long)m * ldc + nc);
            #pragma unroll
            for (int j = 0; j < 4; ++j)
                *(uint4*)(dst + j * 4) = *(uint4*)&u[j * 4];
        } else if (EPI == 2) {
            const float* bp = (const float*)basep + (long)z * bsBase + (long)m * ldc + nc;
            float* o0 = C0 + (long)z * bsC0 + (long)m * ldc + nc;
            float* o1 = C1 + (long)z * bsC1 + (long)m * ldc + nc;
            #pragma unroll
            for (int j = 0; j < 8; ++j) {
                float4 b4 = *(const float4*)(bp + j * 4);
                float4 o; o.x = b4.x + v[j*4]; o.y = b4.y + v[j*4+1];
                o.z = b4.z + v[j*4+2]; o.w = b4.w + v[j*4+3];
                *(float4*)(o0 + j * 4) = o;
                *(float4*)(o1 + j * 4) = o;
            }
        } else {
            const unsigned short* bp = (const unsigned short*)basep + (long)z * bsBase + (long)m * ldc + nc;
            float* o0 = C0 + (long)z * bsC0 + (long)m * ldc + nc;
            float* o1 = C1 + (long)z * bsC1 + (long)m * ldc + nc;
            #pragma unroll
            for (int j = 0; j < 8; ++j) {
                uint2 w = *(const uint2*)(bp + j * 4);
                float4 o;
                o.x = bf2f((unsigned short)(w.x & 0xffffu)) + v[j*4];
                o.y = bf2f((unsigned short)(w.x >> 16))     + v[j*4+1];
                o.z = bf2f((unsigned short)(w.y & 0xffffu)) + v[j*4+2];
                o.w = bf2f((unsigned short)(w.y >> 16))     + v[j*4+3];
                *(float4*)(o0 + j * 4) = o;
                *(float4*)(o1 + j * 4) = o;
            }
        }
    }
}

extern "C" void kernel_launch(void* const* d_in, const int* in_sizes, int n_in,
                              void* d_out, int out_size, void* d_ws, size_t ws_size,
                              hipStream_t stream)
{
    const float* latents = (const float*)d_in[0];
    const float* tokens  = (const float*)d_in[1];
    const float* W_lat   = (const float*)d_in[2];
    const float* W_tok   = (const float*)d_in[3];
    const float* W_vlat  = (const float*)d_in[4];
    const float* W_vtok  = (const float*)d_in[5];
    const float* conv_w  = (const float*)d_in[6];
    const float* conv_b  = (const float*)d_in[7];
    float* out = (float*)d_out;
    char* ws = (char*)d_ws;

    // workspace layout (bytes)
    unsigned short* S    = (unsigned short*)(ws);              // 8x1024x2048 bf16 = 33,554,432
    unsigned short* ST   = (unsigned short*)(ws + 33554432);   // 8x2048x1024 bf16
    unsigned short* tokb = (unsigned short*)(ws + 67108864);   // 8x2048x512  bf16 = 16,777,216
    unsigned short* latb = (unsigned short*)(ws + 83886080);   // 8x1024x512  bf16 =  8,388,608
    unsigned short* rlat = (unsigned short*)(ws + 92274688);   //  8,388,608
    unsigned short* rtok = (unsigned short*)(ws + 100663296);  // 16,777,216
    unsigned short* vlT  = (unsigned short*)(ws + 117440512);  // 8x512x1024 =  8,388,608
    unsigned short* vtT  = (unsigned short*)(ws + 125829120);  // 8x512x2048 = 16,777,216
    unsigned short* wpb  = (unsigned short*)(ws + 142606336);  // 512x1280   =  1,310,720
    unsigned short* wlb  = (unsigned short*)(ws + 143917056);  // 512x512 x4 =  2,097,152
    unsigned short* wtb  = (unsigned short*)(ws + 144441344);
    unsigned short* wvlb = (unsigned short*)(ws + 144965632);
    unsigned short* wvtb = (unsigned short*)(ws + 145489920);  // end 146,014,208
    // tokens-as-bf16 scratch lives in the concat region of d_out (overwritten later)
    unsigned short* tknb = (unsigned short*)(out + 12582912);  // 41,943,040 B <= 50,331,648 B

    // 1) conversions + conv weight pack
    cvt_tl<<<4096, 256, 0, stream>>>((const float4*)tokens, (const float4*)latents,
                                     (ushort4*)tknb, (ushort4*)latb);
    prep_rest<<<512, 256, 0, stream>>>(
        (const float4*)W_lat, (const float4*)W_tok,
        (const float4*)W_vlat, (const float4*)W_vtok, conv_w,
        (ushort4*)wlb, (ushort4*)wtb, (ushort4*)wvlb, (ushort4*)wvtb,
        (unsigned int*)wpb);

    // 2) conv-as-GEMM: tok_bf[16384][512], +bias
    mm_nt<1, 1><<<dim3(4, 128, 1), 256, 0, stream>>>(
        tknb, wpb, 0, 0, 1280, 1280, 1280,
        tokb, 0, nullptr, 0, nullptr, 0, conv_b, 0, 512, 1.f);

    // 3) projections (batches folded into M)
    mm_nt<0, 0><<<dim3(4, 64, 1), 256, 0, stream>>>(
        latb, wlb, 0, 0, 512, 512, 512, rlat, 0, nullptr, 0, nullptr, 0, nullptr, 0, 512, 1.f);
    mm_nt<0, 0><<<dim3(4, 128, 1), 256, 0, stream>>>(
        tokb, wtb, 0, 0, 512, 512, 512, rtok, 0, nullptr, 0, nullptr, 0, nullptr, 0, 512, 1.f);
    // V projections computed transposed: VT[e, l] = sum_d W[e,d] X[l,d]
    mm_nt<0, 0><<<dim3(8, 4, 8), 256, 0, stream>>>(
        wvlb, latb, 0, 524288, 512, 512, 512, vlT, 524288, nullptr, 0, nullptr, 0, nullptr, 0, 1024, 1.f);
    mm_nt<0, 0><<<dim3(16, 4, 8), 256, 0, stream>>>(
        wvtb, tokb, 0, 1048576, 512, 512, 512, vtT, 1048576, nullptr, 0, nullptr, 0, nullptr, 0, 2048, 1.f);

    // 4) score matrix S = scale * Rlat Rtok^T; ST by transpose (same bf16 values)
    mm_nt<0, 0><<<dim3(16, 8, 8), 256, 0, stream>>>(
        rlat, rtok, 524288, 1048576, 512, 512, 512, S, 2097152, nullptr, 0, nullptr, 0, nullptr, 0, 2048, SCALEF);
    transpose_bf<<<dim3(32, 16, 8), 256, 0, stream>>>(S, ST);

    // 5) softmax in place, both matrices, one launch
    softmax_both<<<24576, 256, 0, stream>>>(S, ST);

    // 6) delta GEMMs with fused residual + dual write (own region + concat region)
    mm_nt<0, 2><<<dim3(4, 8, 8), 256, 0, stream>>>(
        S, vtT, 2097152, 1048576, 2048, 2048, 2048,
        nullptr, 0, out, 524288, out + 12582912, 1572864, latents, 524288, 512, 1.f);
    mm_nt<0, 3><<<dim3(4, 16, 8), 256, 0, stream>>>(
        ST, vlT, 2097152, 524288, 1024, 1024, 1024,
        nullptr, 0, out + 4194304, 1048576, out + 12582912 + 524288, 1572864, tokb, 1048576, 512, 1.f);
}

// Round 8
// 244.734 us; speedup vs baseline: 1.3334x; 1.1679x over previous
//
#include <hip/hip_runtime.h>
#include <math.h>

#define SCALEF 0.044194173824159216f   // 1/sqrt(512)

typedef __attribute__((ext_vector_type(8))) short bf16x8;
typedef __attribute__((ext_vector_type(4))) float f32x4;

static __device__ __forceinline__ unsigned short f2bf(float f) {
    union { float f; unsigned int i; } v; v.f = f;
    return (unsigned short)((v.i + 0x7fffu + ((v.i >> 16) & 1u)) >> 16);
}
static __device__ __forceinline__ float bf2f(unsigned short h) {
    union { unsigned int i; float f; } v; v.i = ((unsigned int)h) << 16;
    return v.f;
}
static __device__ __forceinline__ void gload16(const void* g, void* l) {
    __builtin_amdgcn_global_load_lds(
        (const __attribute__((address_space(1))) unsigned int*)g,
        (__attribute__((address_space(3))) unsigned int*)l, 16, 0, 0);
}

// ---- tokens + latents f32 -> bf16, branch-free, 6 independent loads/thread --
__global__ __launch_bounds__(256) void cvt_tl(const float4* __restrict__ tok,
                                              const float4* __restrict__ lat,
                                              ushort4* __restrict__ tokd,
                                              ushort4* __restrict__ latd) {
    long t = blockIdx.x * 256L + threadIdx.x;       // grid 4096 -> 1,048,576 threads
    #pragma unroll
    for (int k = 0; k < 5; ++k) {
        long i = t + k * 1048576L;
        float4 f = tok[i];
        ushort4 u; u.x = f2bf(f.x); u.y = f2bf(f.y); u.z = f2bf(f.z); u.w = f2bf(f.w);
        tokd[i] = u;
    }
    {
        float4 f = lat[t];
        ushort4 u; u.x = f2bf(f.x); u.y = f2bf(f.y); u.z = f2bf(f.z); u.w = f2bf(f.w);
        latd[t] = u;
    }
}

// ---- rest of prep: 4 weights + conv pack ----
__global__ __launch_bounds__(256) void prep_rest(
    const float4* __restrict__ wl, const float4* __restrict__ wt,
    const float4* __restrict__ wvl, const float4* __restrict__ wvt,
    const float* __restrict__ cw,
    ushort4* __restrict__ wlb, ushort4* __restrict__ wtb,
    ushort4* __restrict__ wvlb, ushort4* __restrict__ wvtb,
    unsigned int* __restrict__ wpb)
{
    const long NW = 65536, NCV = 327680;
    for (long i = blockIdx.x * 256L + threadIdx.x; i < 4 * NW + NCV;
         i += gridDim.x * 256L) {
        long r = i;
        const float4* s = nullptr; ushort4* d = nullptr;
        if (r < NW) { s = wl; d = wlb; }
        else if ((r -= NW) < NW) { s = wt; d = wtb; }
        else if ((r -= NW) < NW) { s = wvl; d = wvlb; }
        else if ((r -= NW) < NW) { s = wvt; d = wvtb; }
        else {
            r -= NW;  // conv unit: wp[e][k*128+c2] = {cw[e][2c2][k], cw[e][2c2+1][k]}
            long e = r / 640, rr = r % 640, k = rr >> 7, c2 = rr & 127;
            unsigned int lo = f2bf(cw[e * 1280 + (2 * c2) * 5 + k]);
            unsigned int hi = f2bf(cw[e * 1280 + (2 * c2 + 1) * 5 + k]);
            wpb[r] = lo | (hi << 16);
            continue;
        }
        float4 f = s[r];
        ushort4 u; u.x = f2bf(f.x); u.y = f2bf(f.y); u.z = f2bf(f.z); u.w = f2bf(f.w);
        d[r] = u;
    }
}

// ---------------- bf16 transpose: ST[b][s][l] = S[b][l][s] ----------------
__global__ __launch_bounds__(256) void transpose_bf(const unsigned short* __restrict__ S,
                                                    unsigned short* __restrict__ ST) {
    __shared__ unsigned short tl[64][66];
    const int b = blockIdx.z, r0 = blockIdx.y << 6, c0 = blockIdx.x << 6;
    const unsigned short* Sb = S + ((long)b << 21);
    unsigned short* Tb = ST + ((long)b << 21);
    const int t32 = threadIdx.x & 31, trow = threadIdx.x >> 5;
    #pragma unroll
    for (int i = 0; i < 8; ++i) {
        int r = trow + i * 8;
        unsigned int v = *(const unsigned int*)&Sb[(long)(r0 + r) * 2048 + c0 + t32 * 2];
        *(unsigned int*)&tl[r][t32 * 2] = v;
    }
    __syncthreads();
    #pragma unroll
    for (int i = 0; i < 8; ++i) {
        int c = trow + i * 8;
        unsigned int lo = tl[t32 * 2][c], hi = tl[t32 * 2 + 1][c];
        *(unsigned int*)&Tb[(long)(c0 + c) * 1024 + r0 + t32 * 2] = lo | (hi << 16);
    }
}

// ------------- in-place row softmax body (bf16), 1/sum folded in -------------
template<int RL>
static __device__ __forceinline__ void sm_body(unsigned short* __restrict__ rowp,
                                               float* __restrict__ redm,
                                               float* __restrict__ reds) {
    constexpr int U = RL / 512;                 // u32 words per thread
    unsigned int* p = (unsigned int*)rowp;
    const int t = threadIdx.x, lane = t & 63, wid = t >> 6;
    unsigned int u[U];
    float v[2 * U];
    #pragma unroll
    for (int i = 0; i < U; ++i) u[i] = p[t + (i << 8)];
    #pragma unroll
    for (int i = 0; i < U; ++i) {
        v[2 * i]     = bf2f((unsigned short)(u[i] & 0xffffu));
        v[2 * i + 1] = bf2f((unsigned short)(u[i] >> 16));
    }
    float m = -INFINITY;
    #pragma unroll
    for (int i = 0; i < 2 * U; ++i) m = fmaxf(m, v[i]);
    #pragma unroll
    for (int k = 1; k < 64; k <<= 1) m = fmaxf(m, __shfl_xor(m, k));
    if (lane == 0) redm[wid] = m;
    __syncthreads();
    m = fmaxf(fmaxf(redm[0], redm[1]), fmaxf(redm[2], redm[3]));
    float s = 0.f, e[2 * U];
    #pragma unroll
    for (int i = 0; i < 2 * U; ++i) { e[i] = __expf(v[i] - m); s += e[i]; }
    #pragma unroll
    for (int k = 1; k < 64; k <<= 1) s += __shfl_xor(s, k);
    if (lane == 0) reds[wid] = s;
    __syncthreads();
    s = reds[0] + reds[1] + reds[2] + reds[3];
    float inv = 1.f / s;
    #pragma unroll
    for (int i = 0; i < U; ++i) {
        unsigned int lo = f2bf(e[2 * i] * inv);
        unsigned int hi = f2bf(e[2 * i + 1] * inv);
        p[t + (i << 8)] = lo | (hi << 16);
    }
}

__global__ __launch_bounds__(256) void softmax_both(unsigned short* __restrict__ S,
                                                    unsigned short* __restrict__ ST) {
    __shared__ float redm[4], reds[4];
    long b = blockIdx.x;
    if (b < 8192) sm_body<2048>(S + b * 2048L, redm, reds);
    else          sm_body<1024>(ST + (b - 8192) * 1024L, redm, reds);
}

// ---------------- MFMA NT GEMM body: C[m,n] = sum_k A[m,k] * B[n,k] ----------
// 128x128 tile, BK=32, 4 waves (2x2 of 64x64), 16x16x32 bf16 MFMA.
// Triple-buffered LDS, depth-2 prefetch, counted vmcnt (r5-proven loop).
// Scalar epilogue (r5-proven; r7 showed LDS-staged epilogue costs ~32us).
// All config reaches here as compile-time template args or literals at the call
// site (r6 lesson: runtime-selected Cfg aggregate -> scratch -> 2.7x WRITE_SIZE).
template<int AMODE, int EPI>
static __device__ __forceinline__ void mm_body(
    char* __restrict__ smc, int bx, int by, int z,
    const unsigned short* __restrict__ A, const unsigned short* __restrict__ B,
    long bsA, long bsB, int lda, int ldb, int K,
    unsigned short* __restrict__ Cb, long bsCb,
    float* __restrict__ C0, long bsC0, float* __restrict__ C1, long bsC1,
    const void* __restrict__ basep, long bsBase, int ldc, float scale)
{
    const int t = threadIdx.x, lane = t & 63, wid = t >> 6;
    const int m0 = by << 7, n0 = bx << 7;
    const unsigned short* Ab = A + (long)z * bsA;
    const unsigned short* Bb = B + (long)z * bsB;

    const int rA0 = wid * 16 + (lane >> 2);
    const int rA1 = rA0 + 64;
    const int cs0 = (lane & 3) ^ ((rA0 >> 1) & 3);
    const int cs1 = (lane & 3) ^ ((rA1 >> 1) & 3);

    long aoff0, aoff1;
    if (AMODE == 0) {
        aoff0 = (long)(m0 + rA0) * lda + cs0 * 8;
        aoff1 = (long)(m0 + rA1) * lda + cs1 * 8;
    } else {
        int ma = m0 + rA0, mb = m0 + rA1;
        aoff0 = (long)(ma >> 11) * 2621440 + (long)(ma & 2047) * 1280 + cs0 * 8;
        aoff1 = (long)(mb >> 11) * 2621440 + (long)(mb & 2047) * 1280 + cs1 * 8;
    }
    const long boff0 = (long)(n0 + rA0) * ldb + cs0 * 8;
    const long boff1 = (long)(n0 + rA1) * ldb + cs1 * 8;

    const int dA0 = (wid << 10), dA1 = ((wid + 4) << 10);
    const int dB0 = 8192 + (wid << 10), dB1 = 8192 + ((wid + 4) << 10);

    const int wr = wid >> 1, wc = wid & 1;
    const int l15 = lane & 15, cslot = lane >> 4;
    int offA[4], offB[4];
    #pragma unroll
    for (int i = 0; i < 4; ++i) {
        int r = wr * 64 + i * 16 + l15;
        offA[i] = r * 64 + ((cslot ^ ((r >> 1) & 3)) << 4);
        int rb = wc * 64 + i * 16 + l15;
        offB[i] = 8192 + rb * 64 + ((cslot ^ ((rb >> 1) & 3)) << 4);
    }

    f32x4 acc[4][4];
    #pragma unroll
    for (int i = 0; i < 4; ++i)
        #pragma unroll
        for (int j = 0; j < 4; ++j)
            acc[i][j] = (f32x4)(0.f);

#define STAGE(p, ktv) do {                                   \
        int kb_ = (ktv);                                     \
        int bo_ = (p) * 16384;                               \
        gload16(Ab + aoff0 + kb_, smc + bo_ + dA0);          \
        gload16(Ab + aoff1 + kb_, smc + bo_ + dA1);          \
        gload16(Bb + boff0 + kb_, smc + bo_ + dB0);          \
        gload16(Bb + boff1 + kb_, smc + bo_ + dB1);          \
    } while (0)

    const int nt = K >> 5;                      // always >= 2 here
    STAGE(0, 0);
    STAGE(1, 32);
    int cur = 0;
    for (int it = 0; it < nt; ++it) {
        if (it + 2 < nt) {
            int nx2 = (cur >= 1) ? cur - 1 : 2;   // (cur+2)%3
            STAGE(nx2, (it + 2) << 5);
            asm volatile("s_waitcnt vmcnt(8)" ::: "memory");
        } else if (it + 1 < nt) {
            asm volatile("s_waitcnt vmcnt(4)" ::: "memory");
        } else {
            asm volatile("s_waitcnt vmcnt(0)" ::: "memory");
        }
        __builtin_amdgcn_s_barrier();
        const char* base = smc + cur * 16384;
        bf16x8 af[4], bfr[4];
        #pragma unroll
        for (int i = 0; i < 4; ++i) af[i]  = *(const bf16x8*)(base + offA[i]);
        #pragma unroll
        for (int i = 0; i < 4; ++i) bfr[i] = *(const bf16x8*)(base + offB[i]);
        #pragma unroll
        for (int i = 0; i < 4; ++i)
            #pragma unroll
            for (int j = 0; j < 4; ++j)
                acc[i][j] = __builtin_amdgcn_mfma_f32_16x16x32_bf16(af[i], bfr[j], acc[i][j], 0, 0, 0);
        asm volatile("s_waitcnt lgkmcnt(0)" ::: "memory");
        __builtin_amdgcn_s_barrier();
        cur = (cur + 1 == 3) ? 0 : cur + 1;
    }
#undef STAGE

    // epilogue: C/D frag layout col=lane&15, row=(lane>>4)*4+q  [m89-verified]
    const int colb = n0 + wc * 64 + l15;
    const int rowb = m0 + wr * 64 + cslot * 4;
    #pragma unroll
    for (int i = 0; i < 4; ++i) {
        #pragma unroll
        for (int j = 0; j < 4; ++j) {
            int n = colb + j * 16;
            #pragma unroll
            for (int q = 0; q < 4; ++q) {
                int m = rowb + i * 16 + q;
                float v = acc[i][j][q];
                if (EPI == 0) {
                    Cb[(long)z * bsCb + (long)m * ldc + n] = f2bf(v * scale);
                } else if (EPI == 1) {
                    v += ((const float*)basep)[n];
                    Cb[(long)m * ldc + n] = f2bf(v);
                } else if (EPI == 2) {
                    float bv = ((const float*)basep)[(long)z * bsBase + (long)m * ldc + n];
                    float o = bv + v;
                    C0[(long)z * bsC0 + (long)m * ldc + n] = o;
                    C1[(long)z * bsC1 + (long)m * ldc + n] = o;
                } else {
                    float bv = bf2f(((const unsigned short*)basep)[(long)z * bsBase + (long)m * ldc + n]);
                    float o = bv + v;
                    C0[(long)z * bsC0 + (long)m * ldc + n] = o;
                    C1[(long)z * bsC1 + (long)m * ldc + n] = o;
                }
            }
        }
    }
}

// ---- standalone GEMM (score matrix) ----
template<int AMODE, int EPI>
__global__ __launch_bounds__(256) void mm_nt(
    const unsigned short* __restrict__ A, const unsigned short* __restrict__ B,
    long bsA, long bsB, int lda, int ldb, int K,
    unsigned short* __restrict__ Cb, long bsCb,
    float* __restrict__ C0, long bsC0, float* __restrict__ C1, long bsC1,
    const void* __restrict__ basep, long bsBase, int ldc, float scale)
{
    __shared__ unsigned short sm[24576];
    mm_body<AMODE, EPI>((char*)sm, blockIdx.x, blockIdx.y, blockIdx.z,
                        A, B, bsA, bsB, lda, ldb, K, Cb, bsCb,
                        C0, bsC0, C1, bsC1, basep, bsBase, ldc, scale);
}

// ---- grouped phase 1: conv-GEMM (512 blk) + R_lat proj (256) + V_latT (256) --
__global__ __launch_bounds__(256) void gemm_g1(
    const unsigned short* __restrict__ tknb, const unsigned short* __restrict__ wpb,
    const float* __restrict__ conv_b, unsigned short* __restrict__ tokb,
    const unsigned short* __restrict__ latb, const unsigned short* __restrict__ wlb,
    unsigned short* __restrict__ rlat,
    const unsigned short* __restrict__ wvlb, unsigned short* __restrict__ vlT)
{
    __shared__ unsigned short sm[24576];
    char* smc = (char*)sm;
    const int bid = blockIdx.x;
    if (bid < 512) {                            // conv: grid 4x128, K=1280 (longest first)
        int l = bid;
        mm_body<1, 1>(smc, l & 3, l >> 2, 0, tknb, wpb, 0, 0, 1280, 1280, 1280,
                      tokb, 0, nullptr, 0, nullptr, 0, conv_b, 0, 512, 1.f);
    } else if (bid < 768) {                     // R_lat: grid 4x64
        int l = bid - 512;
        mm_body<0, 0>(smc, l & 3, l >> 2, 0, latb, wlb, 0, 0, 512, 512, 512,
                      rlat, 0, nullptr, 0, nullptr, 0, nullptr, 0, 512, 1.f);
    } else {                                    // V_latT: grid 8x4x8
        int l = bid - 768;
        mm_body<0, 0>(smc, l & 7, (l >> 3) & 3, l >> 5, wvlb, latb, 0, 524288,
                      512, 512, 512, vlT, 524288, nullptr, 0, nullptr, 0,
                      nullptr, 0, 1024, 1.f);
    }
}

// ---- grouped phase 2: R_tok proj (512 blk) + V_tokT (512) ----
__global__ __launch_bounds__(256) void gemm_g2(
    const unsigned short* __restrict__ tokb, const unsigned short* __restrict__ wtb,
    unsigned short* __restrict__ rtok,
    const unsigned short* __restrict__ wvtb, unsigned short* __restrict__ vtT)
{
    __shared__ unsigned short sm[24576];
    char* smc = (char*)sm;
    const int bid = blockIdx.x;
    if (bid < 512) {                            // R_tok: grid 4x128
        int l = bid;
        mm_body<0, 0>(smc, l & 3, l >> 2, 0, tokb, wtb, 0, 0, 512, 512, 512,
                      rtok, 0, nullptr, 0, nullptr, 0, nullptr, 0, 512, 1.f);
    } else {                                    // V_tokT: grid 16x4x8
        int l = bid - 512;
        mm_body<0, 0>(smc, l & 15, (l >> 4) & 3, l >> 6, wvtb, tokb, 0, 1048576,
                      512, 512, 512, vtT, 1048576, nullptr, 0, nullptr, 0,
                      nullptr, 0, 2048, 1.f);
    }
}

// ---- grouped phase 3: both delta GEMMs, fused residual + dual write ----
__global__ __launch_bounds__(256) void gemm_g3(
    const unsigned short* __restrict__ S, const unsigned short* __restrict__ ST,
    const unsigned short* __restrict__ vlT, const unsigned short* __restrict__ vtT,
    const float* __restrict__ latents, const unsigned short* __restrict__ tokb,
    float* __restrict__ out)
{
    __shared__ unsigned short sm[24576];
    char* smc = (char*)sm;
    const int bid = blockIdx.x;
    if (bid < 256) {                            // delta_lat: grid 4x8x8, K=2048 (longest first)
        int l = bid;
        mm_body<0, 2>(smc, l & 3, (l >> 2) & 7, l >> 5, S, vtT, 2097152, 1048576,
                      2048, 2048, 2048, nullptr, 0,
                      out, 524288, out + 12582912, 1572864,
                      latents, 524288, 512, 1.f);
    } else {                                    // delta_tok: grid 4x16x8, K=1024
        int l = bid - 256;
        mm_body<0, 3>(smc, l & 3, (l >> 2) & 15, l >> 6, ST, vlT, 2097152, 524288,
                      1024, 1024, 1024, nullptr, 0,
                      out + 4194304, 1048576, out + 12582912 + 524288, 1572864,
                      tokb, 1048576, 512, 1.f);
    }
}

extern "C" void kernel_launch(void* const* d_in, const int* in_sizes, int n_in,
                              void* d_out, int out_size, void* d_ws, size_t ws_size,
                              hipStream_t stream)
{
    const float* latents = (const float*)d_in[0];
    const float* tokens  = (const float*)d_in[1];
    const float* W_lat   = (const float*)d_in[2];
    const float* W_tok   = (const float*)d_in[3];
    const float* W_vlat  = (const float*)d_in[4];
    const float* W_vtok  = (const float*)d_in[5];
    const float* conv_w  = (const float*)d_in[6];
    const float* conv_b  = (const float*)d_in[7];
    float* out = (float*)d_out;
    char* ws = (char*)d_ws;

    // workspace layout (bytes)
    unsigned short* S    = (unsigned short*)(ws);              // 8x1024x2048 bf16 = 33,554,432
    unsigned short* ST   = (unsigned short*)(ws + 33554432);   // 8x2048x1024 bf16
    unsigned short* tokb = (unsigned short*)(ws + 67108864);   // 8x2048x512  bf16 = 16,777,216
    unsigned short* latb = (unsigned short*)(ws + 83886080);   // 8x1024x512  bf16 =  8,388,608
    unsigned short* rlat = (unsigned short*)(ws + 92274688);   //  8,388,608
    unsigned short* rtok = (unsigned short*)(ws + 100663296);  // 16,777,216
    unsigned short* vlT  = (unsigned short*)(ws + 117440512);  // 8x512x1024 =  8,388,608
    unsigned short* vtT  = (unsigned short*)(ws + 125829120);  // 8x512x2048 = 16,777,216
    unsigned short* wpb  = (unsigned short*)(ws + 142606336);  // 512x1280   =  1,310,720
    unsigned short* wlb  = (unsigned short*)(ws + 143917056);  // 512x512 x4 =  2,097,152
    unsigned short* wtb  = (unsigned short*)(ws + 144441344);
    unsigned short* wvlb = (unsigned short*)(ws + 144965632);
    unsigned short* wvtb = (unsigned short*)(ws + 145489920);  // end 146,014,208
    // tokens-as-bf16 scratch lives in the concat region of d_out (overwritten by g3)
    unsigned short* tknb = (unsigned short*)(out + 12582912);  // 41,943,040 B <= 50,331,648 B

    // 1) conversions + conv weight pack
    cvt_tl<<<4096, 256, 0, stream>>>((const float4*)tokens, (const float4*)latents,
                                     (ushort4*)tknb, (ushort4*)latb);
    prep_rest<<<512, 256, 0, stream>>>(
        (const float4*)W_lat, (const float4*)W_tok,
        (const float4*)W_vlat, (const float4*)W_vtok, conv_w,
        (ushort4*)wlb, (ushort4*)wtb, (ushort4*)wvlb, (ushort4*)wvtb,
        (unsigned int*)wpb);

    // 2) conv-GEMM + latent-side projections (one launch, 1024 blocks)
    gemm_g1<<<1024, 256, 0, stream>>>(tknb, wpb, conv_b, tokb,
                                      latb, wlb, rlat, wvlb, vlT);

    // 3) token-side projections (one launch, 1024 blocks)
    gemm_g2<<<1024, 256, 0, stream>>>(tokb, wtb, rtok, wvtb, vtT);

    // 4) score matrix S = scale * Rlat Rtok^T; ST by transpose (same bf16 values)
    mm_nt<0, 0><<<dim3(16, 8, 8), 256, 0, stream>>>(
        rlat, rtok, 524288, 1048576, 512, 512, 512, S, 2097152,
        nullptr, 0, nullptr, 0, nullptr, 0, 2048, SCALEF);
    transpose_bf<<<dim3(32, 16, 8), 256, 0, stream>>>(S, ST);

    // 5) softmax in place, both matrices, one launch
    softmax_both<<<24576, 256, 0, stream>>>(S, ST);

    // 6) both delta GEMMs (one launch, 768 blocks)
    gemm_g3<<<768, 256, 0, stream>>>(S, ST, vlT, vtT, latents, tokb, out);
}

// Round 9
// 226.633 us; speedup vs baseline: 1.4399x; 1.0799x over previous
//
#include <hip/hip_runtime.h>
#include <math.h>

#define SCALEF 0.044194173824159216f   // 1/sqrt(512)

typedef __attribute__((ext_vector_type(8))) short bf16x8;
typedef __attribute__((ext_vector_type(4))) float f32x4;

static __device__ __forceinline__ unsigned short f2bf(float f) {
    union { float f; unsigned int i; } v; v.f = f;
    return (unsigned short)((v.i + 0x7fffu + ((v.i >> 16) & 1u)) >> 16);
}
static __device__ __forceinline__ float bf2f(unsigned short h) {
    union { unsigned int i; float f; } v; v.i = ((unsigned int)h) << 16;
    return v.f;
}
static __device__ __forceinline__ void gload16(const void* g, void* l) {
    __builtin_amdgcn_global_load_lds(
        (const __attribute__((address_space(1))) unsigned int*)g,
        (__attribute__((address_space(3))) unsigned int*)l, 16, 0, 0);
}
// bijective XCD-chunked swizzle (m157/m204): blocks sharing panels land on one XCD.
// n must be a multiple of 8 (all our job sizes are).
static __device__ __forceinline__ int swz(int l, int n) {
    return (l & 7) * (n >> 3) + (l >> 3);
}

// ---- tokens + latents f32 -> bf16, branch-free, 6 independent loads/thread --
__global__ __launch_bounds__(256) void cvt_tl(const float4* __restrict__ tok,
                                              const float4* __restrict__ lat,
                                              ushort4* __restrict__ tokd,
                                              ushort4* __restrict__ latd) {
    long t = blockIdx.x * 256L + threadIdx.x;       // grid 4096 -> 1,048,576 threads
    #pragma unroll
    for (int k = 0; k < 5; ++k) {
        long i = t + k * 1048576L;
        float4 f = tok[i];
        ushort4 u; u.x = f2bf(f.x); u.y = f2bf(f.y); u.z = f2bf(f.z); u.w = f2bf(f.w);
        tokd[i] = u;
    }
    {
        float4 f = lat[t];
        ushort4 u; u.x = f2bf(f.x); u.y = f2bf(f.y); u.z = f2bf(f.z); u.w = f2bf(f.w);
        latd[t] = u;
    }
}

// ---- rest of prep: 4 weights + conv pack ----
__global__ __launch_bounds__(256) void prep_rest(
    const float4* __restrict__ wl, const float4* __restrict__ wt,
    const float4* __restrict__ wvl, const float4* __restrict__ wvt,
    const float* __restrict__ cw,
    ushort4* __restrict__ wlb, ushort4* __restrict__ wtb,
    ushort4* __restrict__ wvlb, ushort4* __restrict__ wvtb,
    unsigned int* __restrict__ wpb)
{
    const long NW = 65536, NCV = 327680;
    for (long i = blockIdx.x * 256L + threadIdx.x; i < 4 * NW + NCV;
         i += gridDim.x * 256L) {
        long r = i;
        const float4* s = nullptr; ushort4* d = nullptr;
        if (r < NW) { s = wl; d = wlb; }
        else if ((r -= NW) < NW) { s = wt; d = wtb; }
        else if ((r -= NW) < NW) { s = wvl; d = wvlb; }
        else if ((r -= NW) < NW) { s = wvt; d = wvtb; }
        else {
            r -= NW;  // conv unit: wp[e][k*128+c2] = {cw[e][2c2][k], cw[e][2c2+1][k]}
            long e = r / 640, rr = r % 640, k = rr >> 7, c2 = rr & 127;
            unsigned int lo = f2bf(cw[e * 1280 + (2 * c2) * 5 + k]);
            unsigned int hi = f2bf(cw[e * 1280 + (2 * c2 + 1) * 5 + k]);
            wpb[r] = lo | (hi << 16);
            continue;
        }
        float4 f = s[r];
        ushort4 u; u.x = f2bf(f.x); u.y = f2bf(f.y); u.z = f2bf(f.z); u.w = f2bf(f.w);
        d[r] = u;
    }
}

// ------------- in-place row softmax body (bf16), 1/sum folded in -------------
template<int RL>
static __device__ __forceinline__ void sm_body(unsigned short* __restrict__ rowp,
                                               float* __restrict__ redm,
                                               float* __restrict__ reds) {
    constexpr int U = RL / 512;                 // u32 words per thread
    unsigned int* p = (unsigned int*)rowp;
    const int t = threadIdx.x, lane = t & 63, wid = t >> 6;
    unsigned int u[U];
    float v[2 * U];
    #pragma unroll
    for (int i = 0; i < U; ++i) u[i] = p[t + (i << 8)];
    #pragma unroll
    for (int i = 0; i < U; ++i) {
        v[2 * i]     = bf2f((unsigned short)(u[i] & 0xffffu));
        v[2 * i + 1] = bf2f((unsigned short)(u[i] >> 16));
    }
    float m = -INFINITY;
    #pragma unroll
    for (int i = 0; i < 2 * U; ++i) m = fmaxf(m, v[i]);
    #pragma unroll
    for (int k = 1; k < 64; k <<= 1) m = fmaxf(m, __shfl_xor(m, k));
    if (lane == 0) redm[wid] = m;
    __syncthreads();
    m = fmaxf(fmaxf(redm[0], redm[1]), fmaxf(redm[2], redm[3]));
    float s = 0.f, e[2 * U];
    #pragma unroll
    for (int i = 0; i < 2 * U; ++i) { e[i] = __expf(v[i] - m); s += e[i]; }
    #pragma unroll
    for (int k = 1; k < 64; k <<= 1) s += __shfl_xor(s, k);
    if (lane == 0) reds[wid] = s;
    __syncthreads();
    s = reds[0] + reds[1] + reds[2] + reds[3];
    float inv = 1.f / s;
    #pragma unroll
    for (int i = 0; i < U; ++i) {
        unsigned int lo = f2bf(e[2 * i] * inv);
        unsigned int hi = f2bf(e[2 * i + 1] * inv);
        p[t + (i << 8)] = lo | (hi << 16);
    }
}

__global__ __launch_bounds__(256) void softmax_both(unsigned short* __restrict__ S,
                                                    unsigned short* __restrict__ ST) {
    __shared__ float redm[4], reds[4];
    long b = blockIdx.x;
    if (b < 8192) sm_body<2048>(S + b * 2048L, redm, reds);
    else          sm_body<1024>(ST + (b - 8192) * 1024L, redm, reds);
}

// ---------------- MFMA NT GEMM body: C[m,n] = sum_k A[m,k] * B[n,k] ----------
// 128x128 tile, BK=32, 4 waves (2x2 of 64x64), 16x16x32 bf16 MFMA.
// Triple-buffered LDS, depth-2 prefetch, counted vmcnt (r5-proven loop).
// Scalar epilogue (r5-proven; r7 showed LDS-staged epilogue costs ~32us).
// All config reaches here as compile-time template args or literals at the call
// site (r6 lesson: runtime-selected Cfg aggregate -> scratch -> 2.7x WRITE_SIZE).
// AMODE: 0 = row m at A + m*lda.  1 = conv addressing into raw tokens (bf16).
// EPI:   0 = bf16 out (Cb) * scale
//        1 = +bias(f32, basep) then bf16 out (Cb)
//        2 = f32 base (basep) + acc -> C0 and C1
//        3 = bf16 base (basep) + acc -> C0 and C1
//        4 = bf16 out * scale dual: Cb normal (ldc) AND transposed into
//            (ushort*)C0 with batch stride bsC0, ld bsC1  (score S + S^T)
template<int AMODE, int EPI>
static __device__ __forceinline__ void mm_body(
    char* __restrict__ smc, int bx, int by, int z,
    const unsigned short* __restrict__ A, const unsigned short* __restrict__ B,
    long bsA, long bsB, int lda, int ldb, int K,
    unsigned short* __restrict__ Cb, long bsCb,
    float* __restrict__ C0, long bsC0, float* __restrict__ C1, long bsC1,
    const void* __restrict__ basep, long bsBase, int ldc, float scale)
{
    const int t = threadIdx.x, lane = t & 63, wid = t >> 6;
    const int m0 = by << 7, n0 = bx << 7;
    const unsigned short* Ab = A + (long)z * bsA;
    const unsigned short* Bb = B + (long)z * bsB;

    const int rA0 = wid * 16 + (lane >> 2);
    const int rA1 = rA0 + 64;
    const int cs0 = (lane & 3) ^ ((rA0 >> 1) & 3);
    const int cs1 = (lane & 3) ^ ((rA1 >> 1) & 3);

    long aoff0, aoff1;
    if (AMODE == 0) {
        aoff0 = (long)(m0 + rA0) * lda + cs0 * 8;
        aoff1 = (long)(m0 + rA1) * lda + cs1 * 8;
    } else {
        int ma = m0 + rA0, mb = m0 + rA1;
        aoff0 = (long)(ma >> 11) * 2621440 + (long)(ma & 2047) * 1280 + cs0 * 8;
        aoff1 = (long)(mb >> 11) * 2621440 + (long)(mb & 2047) * 1280 + cs1 * 8;
    }
    const long boff0 = (long)(n0 + rA0) * ldb + cs0 * 8;
    const long boff1 = (long)(n0 + rA1) * ldb + cs1 * 8;

    const int dA0 = (wid << 10), dA1 = ((wid + 4) << 10);
    const int dB0 = 8192 + (wid << 10), dB1 = 8192 + ((wid + 4) << 10);

    const int wr = wid >> 1, wc = wid & 1;
    const int l15 = lane & 15, cslot = lane >> 4;
    int offA[4], offB[4];
    #pragma unroll
    for (int i = 0; i < 4; ++i) {
        int r = wr * 64 + i * 16 + l15;
        offA[i] = r * 64 + ((cslot ^ ((r >> 1) & 3)) << 4);
        int rb = wc * 64 + i * 16 + l15;
        offB[i] = 8192 + rb * 64 + ((cslot ^ ((rb >> 1) & 3)) << 4);
    }

    f32x4 acc[4][4];
    #pragma unroll
    for (int i = 0; i < 4; ++i)
        #pragma unroll
        for (int j = 0; j < 4; ++j)
            acc[i][j] = (f32x4)(0.f);

#define STAGE(p, ktv) do {                                   \
        int kb_ = (ktv);                                     \
        int bo_ = (p) * 16384;                               \
        gload16(Ab + aoff0 + kb_, smc + bo_ + dA0);          \
        gload16(Ab + aoff1 + kb_, smc + bo_ + dA1);          \
        gload16(Bb + boff0 + kb_, smc + bo_ + dB0);          \
        gload16(Bb + boff1 + kb_, smc + bo_ + dB1);          \
    } while (0)

    const int nt = K >> 5;                      // always >= 2 here
    STAGE(0, 0);
    STAGE(1, 32);
    int cur = 0;
    for (int it = 0; it < nt; ++it) {
        if (it + 2 < nt) {
            int nx2 = (cur >= 1) ? cur - 1 : 2;   // (cur+2)%3
            STAGE(nx2, (it + 2) << 5);
            asm volatile("s_waitcnt vmcnt(8)" ::: "memory");
        } else if (it + 1 < nt) {
            asm volatile("s_waitcnt vmcnt(4)" ::: "memory");
        } else {
            asm volatile("s_waitcnt vmcnt(0)" ::: "memory");
        }
        __builtin_amdgcn_s_barrier();
        const char* base = smc + cur * 16384;
        bf16x8 af[4], bfr[4];
        #pragma unroll
        for (int i = 0; i < 4; ++i) af[i]  = *(const bf16x8*)(base + offA[i]);
        #pragma unroll
        for (int i = 0; i < 4; ++i) bfr[i] = *(const bf16x8*)(base + offB[i]);
        #pragma unroll
        for (int i = 0; i < 4; ++i)
            #pragma unroll
            for (int j = 0; j < 4; ++j)
                acc[i][j] = __builtin_amdgcn_mfma_f32_16x16x32_bf16(af[i], bfr[j], acc[i][j], 0, 0, 0);
        asm volatile("s_waitcnt lgkmcnt(0)" ::: "memory");
        __builtin_amdgcn_s_barrier();
        cur = (cur + 1 == 3) ? 0 : cur + 1;
    }
#undef STAGE

    // epilogue: C/D frag layout col=lane&15, row=(lane>>4)*4+q  [m89-verified]
    const int colb = n0 + wc * 64 + l15;
    const int rowb = m0 + wr * 64 + cslot * 4;
    if (EPI == 4) {
        unsigned short* STp = (unsigned short*)C0;
        #pragma unroll
        for (int i = 0; i < 4; ++i) {
            #pragma unroll
            for (int j = 0; j < 4; ++j) {
                int n = colb + j * 16;
                int mb = rowb + i * 16;
                float v0 = acc[i][j][0] * scale, v1 = acc[i][j][1] * scale;
                float v2 = acc[i][j][2] * scale, v3 = acc[i][j][3] * scale;
                unsigned short b0 = f2bf(v0), b1 = f2bf(v1), b2 = f2bf(v2), b3 = f2bf(v3);
                unsigned short* sp = Cb + (long)z * bsCb + (long)mb * ldc + n;
                sp[0] = b0; sp[ldc] = b1; sp[2 * ldc] = b2; sp[3 * ldc] = b3;
                ushort4 st4; st4.x = b0; st4.y = b1; st4.z = b2; st4.w = b3;
                *(ushort4*)(STp + (long)z * bsC0 + (long)n * bsC1 + mb) = st4;
            }
        }
        return;
    }
    #pragma unroll
    for (int i = 0; i < 4; ++i) {
        #pragma unroll
        for (int j = 0; j < 4; ++j) {
            int n = colb + j * 16;
            #pragma unroll
            for (int q = 0; q < 4; ++q) {
                int m = rowb + i * 16 + q;
                float v = acc[i][j][q];
                if (EPI == 0) {
                    Cb[(long)z * bsCb + (long)m * ldc + n] = f2bf(v * scale);
                } else if (EPI == 1) {
                    v += ((const float*)basep)[n];
                    Cb[(long)m * ldc + n] = f2bf(v);
                } else if (EPI == 2) {
                    float bv = ((const float*)basep)[(long)z * bsBase + (long)m * ldc + n];
                    float o = bv + v;
                    C0[(long)z * bsC0 + (long)m * ldc + n] = o;
                    C1[(long)z * bsC1 + (long)m * ldc + n] = o;
                } else {
                    float bv = bf2f(((const unsigned short*)basep)[(long)z * bsBase + (long)m * ldc + n]);
                    float o = bv + v;
                    C0[(long)z * bsC0 + (long)m * ldc + n] = o;
                    C1[(long)z * bsC1 + (long)m * ldc + n] = o;
                }
            }
        }
    }
}

// ---- grouped phase 1: conv-GEMM (512 blk) + R_lat proj (256) + V_latT (256) --
__global__ __launch_bounds__(256) void gemm_g1(
    const unsigned short* __restrict__ tknb, const unsigned short* __restrict__ wpb,
    const float* __restrict__ conv_b, unsigned short* __restrict__ tokb,
    const unsigned short* __restrict__ latb, const unsigned short* __restrict__ wlb,
    unsigned short* __restrict__ rlat,
    const unsigned short* __restrict__ wvlb, unsigned short* __restrict__ vlT)
{
    __shared__ unsigned short sm[24576];
    char* smc = (char*)sm;
    const int bid = blockIdx.x;
    if (bid < 512) {                            // conv: grid 4x128, K=1280 (longest first)
        int l = swz(bid, 512);
        mm_body<1, 1>(smc, l & 3, l >> 2, 0, tknb, wpb, 0, 0, 1280, 1280, 1280,
                      tokb, 0, nullptr, 0, nullptr, 0, conv_b, 0, 512, 1.f);
    } else if (bid < 768) {                     // R_lat: grid 4x64
        int l = swz(bid - 512, 256);
        mm_body<0, 0>(smc, l & 3, l >> 2, 0, latb, wlb, 0, 0, 512, 512, 512,
                      rlat, 0, nullptr, 0, nullptr, 0, nullptr, 0, 512, 1.f);
    } else {                                    // V_latT: grid 8x4x8
        int l = swz(bid - 768, 256);
        mm_body<0, 0>(smc, l & 7, (l >> 3) & 3, l >> 5, wvlb, latb, 0, 524288,
                      512, 512, 512, vlT, 524288, nullptr, 0, nullptr, 0,
                      nullptr, 0, 1024, 1.f);
    }
}

// ---- grouped phase 2: R_tok proj (512 blk) + V_tokT (512) ----
__global__ __launch_bounds__(256) void gemm_g2(
    const unsigned short* __restrict__ tokb, const unsigned short* __restrict__ wtb,
    unsigned short* __restrict__ rtok,
    const unsigned short* __restrict__ wvtb, unsigned short* __restrict__ vtT)
{
    __shared__ unsigned short sm[24576];
    char* smc = (char*)sm;
    const int bid = blockIdx.x;
    if (bid < 512) {                            // R_tok: grid 4x128
        int l = swz(bid, 512);
        mm_body<0, 0>(smc, l & 3, l >> 2, 0, tokb, wtb, 0, 0, 512, 512, 512,
                      rtok, 0, nullptr, 0, nullptr, 0, nullptr, 0, 512, 1.f);
    } else {                                    // V_tokT: grid 16x4x8
        int l = swz(bid - 512, 512);
        mm_body<0, 0>(smc, l & 15, (l >> 4) & 3, l >> 6, wvtb, tokb, 0, 1048576,
                      512, 512, 512, vtT, 1048576, nullptr, 0, nullptr, 0,
                      nullptr, 0, 2048, 1.f);
    }
}

// ---- score GEMM: S = scale * Rlat Rtok^T, dual-written as S and S^T ----
__global__ __launch_bounds__(256) void gemm_sc(
    const unsigned short* __restrict__ rlat, const unsigned short* __restrict__ rtok,
    unsigned short* __restrict__ S, unsigned short* __restrict__ ST)
{
    __shared__ unsigned short sm[24576];
    int l = swz((int)blockIdx.x, 1024);         // grid 16x8x8: one z per XCD chunk
    mm_body<0, 4>((char*)sm, l & 15, (l >> 4) & 7, l >> 7,
                  rlat, rtok, 524288, 1048576, 512, 512, 512,
                  S, 2097152, (float*)ST, 2097152, nullptr, 1024,
                  nullptr, 0, 2048, SCALEF);
}

// ---- grouped phase 3: both delta GEMMs, fused residual + dual write ----
__global__ __launch_bounds__(256) void gemm_g3(
    const unsigned short* __restrict__ S, const unsigned short* __restrict__ ST,
    const unsigned short* __restrict__ vlT, const unsigned short* __restrict__ vtT,
    const float* __restrict__ latents, const unsigned short* __restrict__ tokb,
    float* __restrict__ out)
{
    __shared__ unsigned short sm[24576];
    char* smc = (char*)sm;
    const int bid = blockIdx.x;
    if (bid < 256) {                            // delta_lat: grid 4x8x8, K=2048 (longest first)
        int l = swz(bid, 256);
        mm_body<0, 2>(smc, l & 3, (l >> 2) & 7, l >> 5, S, vtT, 2097152, 1048576,
                      2048, 2048, 2048, nullptr, 0,
                      out, 524288, out + 12582912, 1572864,
                      latents, 524288, 512, 1.f);
    } else {                                    // delta_tok: grid 4x16x8, K=1024
        int l = swz(bid - 256, 512);
        mm_body<0, 3>(smc, l & 3, (l >> 2) & 15, l >> 6, ST, vlT, 2097152, 524288,
                      1024, 1024, 1024, nullptr, 0,
                      out + 4194304, 1048576, out + 12582912 + 524288, 1572864,
                      tokb, 1048576, 512, 1.f);
    }
}

extern "C" void kernel_launch(void* const* d_in, const int* in_sizes, int n_in,
                              void* d_out, int out_size, void* d_ws, size_t ws_size,
                              hipStream_t stream)
{
    const float* latents = (const float*)d_in[0];
    const float* tokens  = (const float*)d_in[1];
    const float* W_lat   = (const float*)d_in[2];
    const float* W_tok   = (const float*)d_in[3];
    const float* W_vlat  = (const float*)d_in[4];
    const float* W_vtok  = (const float*)d_in[5];
    const float* conv_w  = (const float*)d_in[6];
    const float* conv_b  = (const float*)d_in[7];
    float* out = (float*)d_out;
    char* ws = (char*)d_ws;

    // workspace layout (bytes)
    unsigned short* S    = (unsigned short*)(ws);              // 8x1024x2048 bf16 = 33,554,432
    unsigned short* ST   = (unsigned short*)(ws + 33554432);   // 8x2048x1024 bf16
    unsigned short* tokb = (unsigned short*)(ws + 67108864);   // 8x2048x512  bf16 = 16,777,216
    unsigned short* latb = (unsigned short*)(ws + 83886080);   // 8x1024x512  bf16 =  8,388,608
    unsigned short* rlat = (unsigned short*)(ws + 92274688);   //  8,388,608
    unsigned short* rtok = (unsigned short*)(ws + 100663296);  // 16,777,216
    unsigned short* vlT  = (unsigned short*)(ws + 117440512);  // 8x512x1024 =  8,388,608
    unsigned short* vtT  = (unsigned short*)(ws + 125829120);  // 8x512x2048 = 16,777,216
    unsigned short* wpb  = (unsigned short*)(ws + 142606336);  // 512x1280   =  1,310,720
    unsigned short* wlb  = (unsigned short*)(ws + 143917056);  // 512x512 x4 =  2,097,152
    unsigned short* wtb  = (unsigned short*)(ws + 144441344);
    unsigned short* wvlb = (unsigned short*)(ws + 144965632);
    unsigned short* wvtb = (unsigned short*)(ws + 145489920);  // end 146,014,208
    // tokens-as-bf16 scratch lives in the concat region of d_out (overwritten by g3)
    unsigned short* tknb = (unsigned short*)(out + 12582912);  // 41,943,040 B <= 50,331,648 B

    // 1) conversions + conv weight pack
    cvt_tl<<<4096, 256, 0, stream>>>((const float4*)tokens, (const float4*)latents,
                                     (ushort4*)tknb, (ushort4*)latb);
    prep_rest<<<512, 256, 0, stream>>>(
        (const float4*)W_lat, (const float4*)W_tok,
        (const float4*)W_vlat, (const float4*)W_vtok, conv_w,
        (ushort4*)wlb, (ushort4*)wtb, (ushort4*)wvlb, (ushort4*)wvtb,
        (unsigned int*)wpb);

    // 2) conv-GEMM + latent-side projections (one launch, 1024 blocks)
    gemm_g1<<<1024, 256, 0, stream>>>(tknb, wpb, conv_b, tokb,
                                      latb, wlb, rlat, wvlb, vlT);

    // 3) token-side projections (one launch, 1024 blocks)
    gemm_g2<<<1024, 256, 0, stream>>>(tokb, wtb, rtok, wvtb, vtT);

    // 4) score matrix, dual-written as S and S^T (no transpose kernel)
    gemm_sc<<<1024, 256, 0, stream>>>(rlat, rtok, S, ST);

    // 5) softmax in place, both matrices, one launch
    softmax_both<<<24576, 256, 0, stream>>>(S, ST);

    // 6) both delta GEMMs (one launch, 768 blocks)
    gemm_g3<<<768, 256, 0, stream>>>(S, ST, vlT, vtT, latents, tokb, out);
}